// Round 11
// baseline (109.720 us; speedup 1.0000x reference)
//
#include <hip/hip_runtime.h>
#include <hip/hip_bf16.h>

// MMD loss via bf16 MFMA Gram matrix.
// R11: barrier-free deep register pipeline. The untested cell in the ablation
// matrix: deep prefetch + preserved occupancy + NO inter-wave coupling.
// (R9's deep pipe was confounded: 64KB LDS -> 2blk/CU AND 2 barriers/chunk;
// R5's "depth-2" collapsed to depth-1 via its copy chain; all LDS variants
// couple 4 waves to the slowest load at every chunk barrier.)
// Now: 3 rotating register slots, fully unrolled; chunk k+3's 8 loads issue
// right after chunk k's MFMAs free the slot -> ~2.5 chunk-periods (~600cy)
// load-to-use cover; each wave waits only its own counted vmcnt (compiler-
// inserted), no barriers until the final reduce. VGPR ~190 < 256 -> 2
// waves/SIMD retained. Epilogue = R10 chain-parallel form (small win).
// Traffic doubles vs LDS path - R7 proved traffic is not the binder.
//
// Zc layout: Zc[ck][row][32], stored quad = q ^ ((row>>1)&3); each mfma
// fragment = one contiguous coalesced 1KB block per 16 lanes.
// Lessons: no __threadfence; no scattered vector loads; no s_barrier
// alignment (R3); no 1 wave/SIMD (R4); no barrier-coupled deep pipe (R9);
// epilogue chain-parallelism helps ~1us (R10).
//
// z = [xf; yf] (8192 x 256). result = (1/4096^2)*(8192*NSIG + sum_{i<j} 2 s_i s_j K_ij)
// ws: [0,4MiB) bf16 Zc; float norms[8192]; float partials[2080].

#define NSIG 5
#define CKS   262144                 // chunk stride in ushorts: 8192 rows * 32
#define NBLK2 2080                   // 64-supergrid triangle: 64*65/2

typedef __attribute__((ext_vector_type(8))) short short8;
typedef __attribute__((ext_vector_type(4))) float floatx4;

// ---- prep: (B,C,H,W) fp32 -> Zc chunked-swizzled bf16 + norms (unchanged) ----
__global__ __launch_bounds__(256) void prep_kernel(const float* __restrict__ x,
                                                   const float* __restrict__ y,
                                                   ushort* __restrict__ Zc,
                                                   float* __restrict__ norms) {
    const int bid = blockIdx.x;           // s(1) | b(2) | strip(6)
    const int t = threadIdx.x;
    const int s = bid >> 8;
    const int b = (bid >> 6) & 3;
    const int p0 = (bid & 63) << 4;
    const float* src = s ? y : x;
    const int n0 = (s << 12) + (b << 10) + p0;

    __shared__ float tile[256][17];

    const int cg = t >> 2;
    const int p4 = (t & 3) << 2;
#pragma unroll
    for (int pass = 0; pass < 4; ++pass) {
        const int c = cg + (pass << 6);
        const float4 v = *(const float4*)(src + (((size_t)((b << 8) + c)) << 10) + p0 + p4);
        tile[c][p4] = v.x; tile[c][p4 + 1] = v.y; tile[c][p4 + 2] = v.z; tile[c][p4 + 3] = v.w;
    }
    __syncthreads();

    const int r = t >> 4;
    const int q = t & 15;
    const int row = n0 + r;
    const int sw = (row >> 1) & 3;
    float nsum = 0.f;
#pragma unroll
    for (int h = 0; h < 2; ++h) {
        const int j = q + (h << 4);
        const int ck = j >> 2;
        const int sq = (j & 3) ^ sw;
        const int c0 = j << 3;
        uint pk[4];
#pragma unroll
        for (int jj = 0; jj < 4; ++jj) {
            const float f0 = tile[c0 + 2 * jj][r];
            const float f1 = tile[c0 + 2 * jj + 1][r];
            const __hip_bfloat16 h0 = __float2bfloat16(f0);
            const __hip_bfloat16 h1 = __float2bfloat16(f1);
            const float q0 = __bfloat162float(h0), q1 = __bfloat162float(h1);
            nsum = fmaf(q0, q0, nsum);
            nsum = fmaf(q1, q1, nsum);
            pk[jj] = (uint)(*(const ushort*)&h0) | ((uint)(*(const ushort*)&h1) << 16);
        }
        *(uint4*)(Zc + (size_t)ck * CKS + (size_t)row * 32 + (sq << 3)) =
            make_uint4(pk[0], pk[1], pk[2], pk[3]);
    }
#pragma unroll
    for (int off = 1; off < 16; off <<= 1) nsum += __shfl_xor(nsum, off, 32);
    if (q == 0) norms[row] = nsum;
}

// ---- GEMM: 4-wave blocks, 64x64 wave tiles, 3-slot register pipeline ----
__global__ __launch_bounds__(256) void gemm_epi(const ushort* __restrict__ Zc,
                                                const float* __restrict__ norms,
                                                const float* __restrict__ sigmas,
                                                float* __restrict__ partials) {
    __shared__ float wsum[4];

    const int t = threadIdx.x;
    const int w = t >> 6, l = t & 63;
    const int m = l & 15, q = l >> 4;

    // panel decode: panels p of 8 super-columns; P(p) = 32p^2 + 4p blocks before
    // panel p; within panel, column-major (column tj2 has tj2+1 blocks).
    const int lin = blockIdx.x;
    int p = (int)((-4.0f + sqrtf(16.0f + 128.0f * (float)lin)) * (1.0f / 64.0f));
    p = p < 0 ? 0 : (p > 7 ? 7 : p);
    while (p < 7 && 32 * (p + 1) * (p + 1) + 4 * (p + 1) <= lin) ++p;
    while (p > 0 && 32 * p * p + 4 * p > lin) --p;
    const int o = lin - (32 * p * p + 4 * p);
    int c = 7;
#pragma unroll
    for (int cc = 7; cc >= 1; --cc) {
        const int Q = cc * (8 * p + 1) + (cc * (cc - 1)) / 2;
        if (o < Q) c = cc - 1;
    }
    const int Qc = c * (8 * p + 1) + (c * (c - 1)) / 2;
    const int tj2 = 8 * p + c;
    const int ti2 = o - Qc;              // 0..tj2

    // wave -> 64x64 tile: ti = 2*ti2 + (w>>1), tj = 2*tj2 + (w&1)
    const int ti = (ti2 << 1) + (w >> 1);
    const int tj = (tj2 << 1) + (w & 1);
    const bool active = (ti <= tj);      // lower-tri wave of diag supertile idles
    const bool diag = (ti == tj);
    const int i0 = ti << 6, j0 = tj << 6;

    int offA[4], offB[4];
#pragma unroll
    for (int f = 0; f < 4; ++f) {
        const int ra = i0 + (f << 4) + m;
        offA[f] = (ra << 5) + ((q ^ ((ra >> 1) & 3)) << 3);
        const int rb = j0 + (f << 4) + m;
        offB[f] = (rb << 5) + ((q ^ ((rb >> 1) & 3)) << 3);
    }

    floatx4 accf[4][4];
#pragma unroll
    for (int fi = 0; fi < 4; ++fi)
#pragma unroll
        for (int fj = 0; fj < 4; ++fj) accf[fi][fj] = (floatx4){0.f, 0.f, 0.f, 0.f};

    float lsum = 0.f;
    if (active) {
        // 3 rotating register slots, fully static indexing
        short8 A[3][4], B[3][4];

#define LOADSET(s_, k_) do {                                              \
        const size_t ko_ = (size_t)(k_) * CKS;                            \
        _Pragma("unroll")                                                 \
        for (int f = 0; f < 4; ++f) {                                     \
            A[s_][f] = *(const short8*)(Zc + ko_ + offA[f]);              \
            B[s_][f] = *(const short8*)(Zc + ko_ + offB[f]);              \
        }                                                                 \
    } while (0)

#define MFMASET(s_) do {                                                  \
        _Pragma("unroll")                                                 \
        for (int fi = 0; fi < 4; ++fi)                                    \
            _Pragma("unroll")                                             \
            for (int fj = 0; fj < 4; ++fj)                                \
                accf[fi][fj] = __builtin_amdgcn_mfma_f32_16x16x32_bf16(   \
                    A[s_][fi], B[s_][fj], accf[fi][fj], 0, 0, 0);         \
    } while (0)

        // prologue: slots 0,1,2 <- chunks 0,1,2 (24 loads in flight)
        LOADSET(0, 0); LOADSET(1, 1); LOADSET(2, 2);
        // steady state: use slot, refill it with chunk+3
        MFMASET(0); LOADSET(0, 3);
        MFMASET(1); LOADSET(1, 4);
        MFMASET(2); LOADSET(2, 5);
        MFMASET(0); LOADSET(0, 6);
        MFMASET(1); LOADSET(1, 7);
        MFMASET(2);
        MFMASET(0);
        MFMASET(1);

#undef LOADSET
#undef MFMASET

        // ---- epilogue: chain-parallel, vector-shaped (R10) ----
        float c2[NSIG];
#pragma unroll
        for (int k = 0; k < NSIG; ++k) c2[k] = (-0.5f / sigmas[k]) * 1.44269504f;

        const float sgn2 = ((i0 < 4096) == (j0 < 4096)) ? 2.f : -2.f;

        float njs[4];
#pragma unroll
        for (int fj = 0; fj < 4; ++fj) njs[fj] = norms[j0 + (fj << 4) + m];

        // d = max(ni + nj - 2*g, 0) — vector-shaped, no per-element branch
#pragma unroll
        for (int fi = 0; fi < 4; ++fi) {
            const floatx4 ni4 = *(const floatx4*)(norms + i0 + (fi << 4) + (q << 2));
#pragma unroll
            for (int fj = 0; fj < 4; ++fj) {
                floatx4 a = accf[fi][fj];
#pragma unroll
                for (int v = 0; v < 4; ++v)
                    a[v] = fmaxf(fmaf(-2.f, a[v], ni4[v] + njs[fj]), 0.f);
                accf[fi][fj] = a;
            }
        }
        if (diag) {        // wave-uniform rare path: strictly-upper mask
#pragma unroll
            for (int fi = 0; fi < 4; ++fi)
#pragma unroll
                for (int fj = 0; fj < 4; ++fj)
#pragma unroll
                    for (int v = 0; v < 4; ++v) {
                        const int dif = ((fi - fj) << 4) + ((q << 2) + v) - m;   // gi - gj
                        if (dif >= 0) accf[fi][fj][v] = 3.0e9f;
                    }
        }

        // dmin: 4 independent component chains, then 2-level tree + shfl
        floatx4 mn = accf[0][0];
#pragma unroll
        for (int fi = 0; fi < 4; ++fi)
#pragma unroll
            for (int fj = 0; fj < 4; ++fj)
                if (fi | fj) {
#pragma unroll
                    for (int v = 0; v < 4; ++v) mn[v] = fminf(mn[v], accf[fi][fj][v]);
                }
        float dmin = fminf(fminf(mn[0], mn[1]), fminf(mn[2], mn[3]));
#pragma unroll
        for (int off = 1; off < 64; off <<= 1) dmin = fminf(dmin, __shfl_xor(dmin, off, 64));

        // exp accumulate: 8 independent chains (two floatx4 accumulators)
        floatx4 ts0 = (floatx4){0.f, 0.f, 0.f, 0.f};
        floatx4 ts1 = (floatx4){0.f, 0.f, 0.f, 0.f};
#pragma unroll
        for (int k = 0; k < NSIG; ++k) {
            if (c2[k] * dmin >= -126.f) {   // wave-uniform skip iff all exps underflow
                const float ck2 = c2[k];
#pragma unroll
                for (int fi = 0; fi < 4; ++fi)
#pragma unroll
                    for (int fj = 0; fj < 4; ++fj) {
                        const floatx4 a = accf[fi][fj];
                        floatx4 e;
#pragma unroll
                        for (int v = 0; v < 4; ++v)
                            e[v] = __builtin_amdgcn_exp2f(ck2 * a[v]);
                        if ((fj & 1) == 0) ts0 += e; else ts1 += e;
                    }
            }
        }
        ts0 += ts1;
        lsum = sgn2 * ((ts0[0] + ts0[1]) + (ts0[2] + ts0[3]));
    }

    // ---- block reduce + store ----
#pragma unroll
    for (int off = 32; off > 0; off >>= 1) lsum += __shfl_down(lsum, off, 64);
    if (l == 0) wsum[w] = lsum;
    __syncthreads();
    if (t == 0) partials[blockIdx.x] = wsum[0] + wsum[1] + wsum[2] + wsum[3];
}

__global__ __launch_bounds__(256) void finalize_kernel(const float* __restrict__ partials,
                                                       float* __restrict__ out) {
    __shared__ double sh[256];
    const int t = threadIdx.x;
    double s = 0.0;
    for (int i = t; i < NBLK2; i += 256) s += (double)partials[i];
    sh[t] = s;
    __syncthreads();
    for (int st = 128; st > 0; st >>= 1) {
        if (t < st) sh[t] += sh[t + st];
        __syncthreads();
    }
    if (t == 0) out[0] = (float)((sh[0] + 8192.0 * NSIG) * (1.0 / (4096.0 * 4096.0)));
}

extern "C" void kernel_launch(void* const* d_in, const int* in_sizes, int n_in,
                              void* d_out, int out_size, void* d_ws, size_t ws_size,
                              hipStream_t stream) {
    const float* x   = (const float*)d_in[0];
    const float* y   = (const float*)d_in[1];
    const float* sig = (const float*)d_in[2];

    ushort* Zc      = (ushort*)d_ws;                                   // 4 MiB
    float* norms    = (float*)((char*)d_ws + (size_t)8192 * 256 * 2);  // 32 KiB
    float* partials = (float*)((char*)norms + 8192 * sizeof(float));   // 2080 floats
    float* out      = (float*)d_out;

    prep_kernel<<<512, 256, 0, stream>>>(x, y, Zc, norms);
    gemm_epi<<<NBLK2, 256, 0, stream>>>(Zc, norms, sig, partials);
    finalize_kernel<<<1, 256, 0, stream>>>(partials, out);
}

// Round 12
// 94.892 us; speedup vs baseline: 1.1563x; 1.1563x over previous
//
#include <hip/hip_runtime.h>
#include <hip/hip_bf16.h>

// MMD loss via bf16 MFMA Gram matrix.
// R12: R10 (best: 3-buffer LDS ring, counted vmcnt, chain-parallel epilogue)
// + per-block K-chunk ROTATION. Theory: every scheduling variant pinned at
// ~12 TB/s delivered because panel-ordered decode makes all ~512 resident
// blocks hammer the SAME 8KB panel (64 cache lines) simultaneously -> L2
// bank hotspot serialization (insensitive to occupancy/depth/traffic, as
// measured R1-R11). Rotating each block's chunk order by blockIdx&7 spreads
// concurrent demand over 8 panels. K-sum is order-independent.
// R11 lesson: compiler re-sinks deep register pipelines (VGPR 88 proved
// the 3-slot pipe collapsed to depth-1); register-pipeline family dead
// without inline asm.
//
// Zc layout: Zc[ck][row][32], stored quad = q ^ ((row>>1)&3); 128-row panel
// per chunk = contiguous 8KB; supertile base % 128 == 0 keeps the swizzle
// valid on LDS-local rows. glds: wave-uniform LDS base + lane*16B.
//
// z = [xf; yf] (8192 x 256). result = (1/4096^2)*(8192*NSIG + sum_{i<j} 2 s_i s_j K_ij)
// ws: [0,4MiB) bf16 Zc; float norms[8192]; float partials[2080].

#define NSIG 5
#define CKS   262144                 // chunk stride in ushorts: 8192 rows * 32
#define NBLK2 2080                 // 64-supergrid triangle: 64*65/2

typedef __attribute__((ext_vector_type(8))) short short8;
typedef __attribute__((ext_vector_type(4))) float floatx4;

#define GLDS16(gp, lp) __builtin_amdgcn_global_load_lds( \
    (const __attribute__((address_space(1))) void*)(gp),  \
    (__attribute__((address_space(3))) void*)(lp), 16, 0, 0)

// ---- prep: (B,C,H,W) fp32 -> Zc chunked-swizzled bf16 + norms (unchanged) ----
__global__ __launch_bounds__(256) void prep_kernel(const float* __restrict__ x,
                                                   const float* __restrict__ y,
                                                   ushort* __restrict__ Zc,
                                                   float* __restrict__ norms) {
    const int bid = blockIdx.x;           // s(1) | b(2) | strip(6)
    const int t = threadIdx.x;
    const int s = bid >> 8;
    const int b = (bid >> 6) & 3;
    const int p0 = (bid & 63) << 4;
    const float* src = s ? y : x;
    const int n0 = (s << 12) + (b << 10) + p0;

    __shared__ float tile[256][17];

    const int cg = t >> 2;
    const int p4 = (t & 3) << 2;
#pragma unroll
    for (int pass = 0; pass < 4; ++pass) {
        const int c = cg + (pass << 6);
        const float4 v = *(const float4*)(src + (((size_t)((b << 8) + c)) << 10) + p0 + p4);
        tile[c][p4] = v.x; tile[c][p4 + 1] = v.y; tile[c][p4 + 2] = v.z; tile[c][p4 + 3] = v.w;
    }
    __syncthreads();

    const int r = t >> 4;
    const int q = t & 15;
    const int row = n0 + r;
    const int sw = (row >> 1) & 3;
    float nsum = 0.f;
#pragma unroll
    for (int h = 0; h < 2; ++h) {
        const int j = q + (h << 4);
        const int ck = j >> 2;
        const int sq = (j & 3) ^ sw;
        const int c0 = j << 3;
        uint pk[4];
#pragma unroll
        for (int jj = 0; jj < 4; ++jj) {
            const float f0 = tile[c0 + 2 * jj][r];
            const float f1 = tile[c0 + 2 * jj + 1][r];
            const __hip_bfloat16 h0 = __float2bfloat16(f0);
            const __hip_bfloat16 h1 = __float2bfloat16(f1);
            const float q0 = __bfloat162float(h0), q1 = __bfloat162float(h1);
            nsum = fmaf(q0, q0, nsum);
            nsum = fmaf(q1, q1, nsum);
            pk[jj] = (uint)(*(const ushort*)&h0) | ((uint)(*(const ushort*)&h1) << 16);
        }
        *(uint4*)(Zc + (size_t)ck * CKS + (size_t)row * 32 + (sq << 3)) =
            make_uint4(pk[0], pk[1], pk[2], pk[3]);
    }
#pragma unroll
    for (int off = 1; off < 16; off <<= 1) nsum += __shfl_xor(nsum, off, 32);
    if (q == 0) norms[row] = nsum;
}

// ---- GEMM: 4-wave blocks, 128x128 supertile, 3-buffer counted-vmcnt pipe,
// ----       per-block rotated K-chunk order (L2 hotspot decorrelation) ----
__global__ __launch_bounds__(256) void gemm_epi(const ushort* __restrict__ Zc,
                                                const float* __restrict__ norms,
                                                const float* __restrict__ sigmas,
                                                float* __restrict__ partials) {
    __shared__ ushort bufA[3][4096];   // 3 x 8KB: A panel (128 rows x 32)
    __shared__ ushort bufB[3][4096];   // 3 x 8KB: B panel
    __shared__ float wsum[4];

    const int t = threadIdx.x;
    const int w = t >> 6, l = t & 63;
    const int m = l & 15, q = l >> 4;

    // panel decode: panels p of 8 super-columns; P(p) = 32p^2 + 4p blocks before
    // panel p; within panel, column-major (column tj2 has tj2+1 blocks).
    const int lin = blockIdx.x;
    int p = (int)((-4.0f + sqrtf(16.0f + 128.0f * (float)lin)) * (1.0f / 64.0f));
    p = p < 0 ? 0 : (p > 7 ? 7 : p);
    while (p < 7 && 32 * (p + 1) * (p + 1) + 4 * (p + 1) <= lin) ++p;
    while (p > 0 && 32 * p * p + 4 * p > lin) --p;
    const int o = lin - (32 * p * p + 4 * p);
    int c = 7;
#pragma unroll
    for (int cc = 7; cc >= 1; --cc) {
        const int Q = cc * (8 * p + 1) + (cc * (cc - 1)) / 2;
        if (o < Q) c = cc - 1;
    }
    const int Qc = c * (8 * p + 1) + (c * (c - 1)) / 2;
    const int tj2 = 8 * p + c;
    const int ti2 = o - Qc;              // 0..tj2

    const int I0 = ti2 << 7;             // supertile bases (multiples of 128)
    const int J0 = tj2 << 7;

    // wave quadrant: ti = 2*ti2 + (w>>1), tj = 2*tj2 + (w&1)
    const int ti = (ti2 << 1) + (w >> 1);
    const int tj = (tj2 << 1) + (w & 1);
    const bool active = (ti <= tj);      // lower-tri wave of diag supertile: discard
    const bool diag = (ti == tj);
    const int i0 = ti << 6, j0 = tj << 6;

    // LDS fragment read offsets (ushort idx, panel-local rows)
    int loffA[4], loffB[4];
#pragma unroll
    for (int f = 0; f < 4; ++f) {
        const int ra = ((w >> 1) << 6) + (f << 4) + m;
        loffA[f] = (ra << 5) + ((q ^ ((ra >> 1) & 3)) << 3);
        const int rb = ((w & 1) << 6) + (f << 4) + m;
        loffB[f] = (rb << 5) + ((q ^ ((rb >> 1) & 3)) << 3);
    }

    // staging: wave w copies ushorts [w*1024, (w+1)*1024) of each 8KB panel,
    // two glds issues each (lane offset = lane*16B, HW-linear).
    const int sg = (w << 10) + (l << 3);
    const ushort* gA0 = Zc + (size_t)I0 * 32 + sg;
    const ushort* gB0 = Zc + (size_t)J0 * 32 + sg;
    const int lo = w << 10;

    // per-block rotated chunk order: phys chunk byte-offsets, compile-time
    // indexed under full unroll. Decorrelates concurrent panel demand.
    const int rot = lin & 7;
    size_t kb[8];
#pragma unroll
    for (int k = 0; k < 8; ++k) kb[k] = (size_t)((k + rot) & 7) * CKS;

    // prologue: stage phys(0) -> buf0 (oldest 4), phys(1) -> buf1; wait phys(0).
    GLDS16(gA0 + kb[0],       &bufA[0][lo]);
    GLDS16(gA0 + kb[0] + 512, &bufA[0][lo + 512]);
    GLDS16(gB0 + kb[0],       &bufB[0][lo]);
    GLDS16(gB0 + kb[0] + 512, &bufB[0][lo + 512]);
    GLDS16(gA0 + kb[1],       &bufA[1][lo]);
    GLDS16(gA0 + kb[1] + 512, &bufA[1][lo + 512]);
    GLDS16(gB0 + kb[1],       &bufB[1][lo]);
    GLDS16(gB0 + kb[1] + 512, &bufB[1][lo + 512]);
    asm volatile("s_waitcnt vmcnt(4)" ::: "memory");
    __builtin_amdgcn_s_barrier();
    __builtin_amdgcn_sched_barrier(0);

    floatx4 accf[4][4];
#pragma unroll
    for (int fi = 0; fi < 4; ++fi)
#pragma unroll
        for (int fj = 0; fj < 4; ++fj) accf[fi][fj] = (floatx4){0.f, 0.f, 0.f, 0.f};

    // ---- main K loop: 8 chunks, depth-2 glds, counted vmcnt, raw barrier ----
#pragma unroll
    for (int ck = 0; ck < 8; ++ck) {
        const ushort* rA = &bufA[ck % 3][0];
        const ushort* rB = &bufB[ck % 3][0];
        short8 fa[4], fb[4];
#pragma unroll
        for (int f = 0; f < 4; ++f) fa[f] = *(const short8*)(rA + loffA[f]);
#pragma unroll
        for (int f = 0; f < 4; ++f) fb[f] = *(const short8*)(rB + loffB[f]);
        if (ck < 6) {
            const size_t ko = kb[ck + 2];
            const int nb = (ck + 2) % 3;
            GLDS16(gA0 + ko,       &bufA[nb][lo]);
            GLDS16(gA0 + ko + 512, &bufA[nb][lo + 512]);
            GLDS16(gB0 + ko,       &bufB[nb][lo]);
            GLDS16(gB0 + ko + 512, &bufB[nb][lo + 512]);
        }
#pragma unroll
        for (int fi = 0; fi < 4; ++fi)
#pragma unroll
            for (int fj = 0; fj < 4; ++fj)
                accf[fi][fj] = __builtin_amdgcn_mfma_f32_16x16x32_bf16(fa[fi], fb[fj], accf[fi][fj], 0, 0, 0);
        if (ck < 7) {
            if (ck < 6) { asm volatile("s_waitcnt vmcnt(4)" ::: "memory"); }
            else        { asm volatile("s_waitcnt vmcnt(0)" ::: "memory"); }
            __builtin_amdgcn_s_barrier();
            __builtin_amdgcn_sched_barrier(0);
        }
    }

    // ---- epilogue: chain-parallel, vector-shaped (R10) ----
    float lsum = 0.f;
    if (active) {
        float c2[NSIG];
#pragma unroll
        for (int k = 0; k < NSIG; ++k) c2[k] = (-0.5f / sigmas[k]) * 1.44269504f;

        const float sgn2 = ((i0 < 4096) == (j0 < 4096)) ? 2.f : -2.f;

        float njs[4];
#pragma unroll
        for (int fj = 0; fj < 4; ++fj) njs[fj] = norms[j0 + (fj << 4) + m];

        // d = max(ni + nj - 2*g, 0) — vector-shaped, no per-element branch
#pragma unroll
        for (int fi = 0; fi < 4; ++fi) {
            const floatx4 ni4 = *(const floatx4*)(norms + i0 + (fi << 4) + (q << 2));
#pragma unroll
            for (int fj = 0; fj < 4; ++fj) {
                floatx4 a = accf[fi][fj];
#pragma unroll
                for (int v = 0; v < 4; ++v)
                    a[v] = fmaxf(fmaf(-2.f, a[v], ni4[v] + njs[fj]), 0.f);
                accf[fi][fj] = a;
            }
        }
        if (diag) {        // wave-uniform rare path: strictly-upper mask
#pragma unroll
            for (int fi = 0; fi < 4; ++fi)
#pragma unroll
                for (int fj = 0; fj < 4; ++fj)
#pragma unroll
                    for (int v = 0; v < 4; ++v) {
                        const int dif = ((fi - fj) << 4) + ((q << 2) + v) - m;   // gi - gj
                        if (dif >= 0) accf[fi][fj][v] = 3.0e9f;
                    }
        }

        // dmin: 4 independent component chains, then 2-level tree + shfl
        floatx4 mn = accf[0][0];
#pragma unroll
        for (int fi = 0; fi < 4; ++fi)
#pragma unroll
            for (int fj = 0; fj < 4; ++fj)
                if (fi | fj) {
#pragma unroll
                    for (int v = 0; v < 4; ++v) mn[v] = fminf(mn[v], accf[fi][fj][v]);
                }
        float dmin = fminf(fminf(mn[0], mn[1]), fminf(mn[2], mn[3]));
#pragma unroll
        for (int off = 1; off < 64; off <<= 1) dmin = fminf(dmin, __shfl_xor(dmin, off, 64));

        // exp accumulate: 8 independent chains (two floatx4 accumulators)
        floatx4 ts0 = (floatx4){0.f, 0.f, 0.f, 0.f};
        floatx4 ts1 = (floatx4){0.f, 0.f, 0.f, 0.f};
#pragma unroll
        for (int k = 0; k < NSIG; ++k) {
            if (c2[k] * dmin >= -126.f) {   // wave-uniform skip iff all exps underflow
                const float ck2 = c2[k];
#pragma unroll
                for (int fi = 0; fi < 4; ++fi)
#pragma unroll
                    for (int fj = 0; fj < 4; ++fj) {
                        const floatx4 a = accf[fi][fj];
                        floatx4 e;
#pragma unroll
                        for (int v = 0; v < 4; ++v)
                            e[v] = __builtin_amdgcn_exp2f(ck2 * a[v]);
                        if ((fj & 1) == 0) ts0 += e; else ts1 += e;
                    }
            }
        }
        ts0 += ts1;
        lsum = sgn2 * ((ts0[0] + ts0[1]) + (ts0[2] + ts0[3]));
    }

    // ---- block reduce + store ----
#pragma unroll
    for (int off = 32; off > 0; off >>= 1) lsum += __shfl_down(lsum, off, 64);
    if (l == 0) wsum[w] = lsum;
    __syncthreads();
    if (t == 0) partials[blockIdx.x] = wsum[0] + wsum[1] + wsum[2] + wsum[3];
}

__global__ __launch_bounds__(256) void finalize_kernel(const float* __restrict__ partials,
                                                       float* __restrict__ out) {
    __shared__ double sh[256];
    const int t = threadIdx.x;
    double s = 0.0;
    for (int i = t; i < NBLK2; i += 256) s += (double)partials[i];
    sh[t] = s;
    __syncthreads();
    for (int st = 128; st > 0; st >>= 1) {
        if (t < st) sh[t] += sh[t + st];
        __syncthreads();
    }
    if (t == 0) out[0] = (float)((sh[0] + 8192.0 * NSIG) * (1.0 / (4096.0 * 4096.0)));
}

extern "C" void kernel_launch(void* const* d_in, const int* in_sizes, int n_in,
                              void* d_out, int out_size, void* d_ws, size_t ws_size,
                              hipStream_t stream) {
    const float* x   = (const float*)d_in[0];
    const float* y   = (const float*)d_in[1];
    const float* sig = (const float*)d_in[2];

    ushort* Zc      = (ushort*)d_ws;                                   // 4 MiB
    float* norms    = (float*)((char*)d_ws + (size_t)8192 * 256 * 2);  // 32 KiB
    float* partials = (float*)((char*)norms + 8192 * sizeof(float));   // 2080 floats
    float* out      = (float*)d_out;

    prep_kernel<<<512, 256, 0, stream>>>(x, y, Zc, norms);
    gemm_epi<<<NBLK2, 256, 0, stream>>>(Zc, norms, sig, partials);
    finalize_kernel<<<1, 256, 0, stream>>>(partials, out);
}